// Round 1
// baseline (120.252 us; speedup 1.0000x reference)
//
#include <hip/hip_runtime.h>
#include <math.h>

#define LL 768
#define CT 64
#define KD 192
#define OC 1024

// ---------------- K1: logits[i*LL+j] = dot(feat[i,j,:], Wq) + bq ----------------
// 16 lanes per (i,j) pair, float4 loads -> 1KB contiguous per wave. HBM-bound.
__global__ __launch_bounds__(256) void k_logits(const float* __restrict__ feat,
                                                const float* __restrict__ Wq,
                                                const float* __restrict__ bq,
                                                float* __restrict__ logits) {
    int t = threadIdx.x;
    int p = blockIdx.x * 16 + (t >> 4);   // flat (i*LL + j)
    int q = t & 15;
    const float4 f = *reinterpret_cast<const float4*>(feat + (size_t)p * CT + q * 4);
    const float4 w = *reinterpret_cast<const float4*>(Wq + q * 4);
    float s = f.x * w.x + f.y * w.y + f.z * w.z + f.w * w.w;
    s += __shfl_xor(s, 1);
    s += __shfl_xor(s, 2);
    s += __shfl_xor(s, 4);
    s += __shfl_xor(s, 8);
    if (q == 0) logits[p] = s + bq[0];
}

// ---------------- K2: per-row and per-col max + sum(exp) ----------------
// stats layout: [0,LL)=rmax [LL,2LL)=rsum [2LL,3LL)=cmax [3LL,4LL)=csum
__global__ __launch_bounds__(256) void k_stats(const float* __restrict__ logits,
                                               float* __restrict__ stats) {
    __shared__ float redm[4], reds[4];
    int b = blockIdx.x, t = threadIdx.x;
    int wid = t >> 6;

    // ---- row b (softmax over j) ----
    float v0 = logits[b * LL + t];
    float v1 = logits[b * LL + t + 256];
    float v2 = logits[b * LL + t + 512];
    float m = fmaxf(fmaxf(v0, v1), v2);
    #pragma unroll
    for (int o = 32; o; o >>= 1) m = fmaxf(m, __shfl_xor(m, o));
    if ((t & 63) == 0) redm[wid] = m;
    __syncthreads();
    float M = fmaxf(fmaxf(redm[0], redm[1]), fmaxf(redm[2], redm[3]));
    float s = expf(v0 - M) + expf(v1 - M) + expf(v2 - M);
    #pragma unroll
    for (int o = 32; o; o >>= 1) s += __shfl_xor(s, o);
    if ((t & 63) == 0) reds[wid] = s;
    __syncthreads();
    if (t == 0) {
        stats[b] = M;
        stats[LL + b] = reds[0] + reds[1] + reds[2] + reds[3];
    }
    __syncthreads();

    // ---- col b (softmax over i) ----
    v0 = logits[(size_t)t * LL + b];
    v1 = logits[(size_t)(t + 256) * LL + b];
    v2 = logits[(size_t)(t + 512) * LL + b];
    m = fmaxf(fmaxf(v0, v1), v2);
    #pragma unroll
    for (int o = 32; o; o >>= 1) m = fmaxf(m, __shfl_xor(m, o));
    if ((t & 63) == 0) redm[wid] = m;
    __syncthreads();
    M = fmaxf(fmaxf(redm[0], redm[1]), fmaxf(redm[2], redm[3]));
    s = expf(v0 - M) + expf(v1 - M) + expf(v2 - M);
    #pragma unroll
    for (int o = 32; o; o >>= 1) s += __shfl_xor(s, o);
    if ((t & 63) == 0) reds[wid] = s;
    __syncthreads();
    if (t == 0) {
        stats[2 * LL + b] = M;
        stats[3 * LL + b] = reds[0] + reds[1] + reds[2] + reds[3];
    }
}

// ---------------- K3: weighted reductions ----------------
// blocks [0,LL): row mode  -> rfeat[i,c] = sum_j w_row[i,j] feat[i,j,c]
// blocks [LL,2LL): col mode-> cfeat[j,c] = sum_i w_col[i,j] feat[i,j,c]
// rcfeat layout: [0, LL*CT)=rfeat, [LL*CT, 2*LL*CT)=cfeat
__global__ __launch_bounds__(256) void k_wsum(const float* __restrict__ feat,
                                              const float* __restrict__ logits,
                                              const float* __restrict__ stats,
                                              float* __restrict__ rcfeat) {
    __shared__ float wbuf[LL];
    __shared__ float part[16][64];
    int t = threadIdx.x;
    int b = blockIdx.x;
    int colmode = b >= LL;
    int rc = colmode ? b - LL : b;
    float M = stats[(colmode ? 2 * LL : 0) + rc];
    float inv = 1.0f / stats[(colmode ? 3 * LL : LL) + rc];
    for (int x = t; x < LL; x += 256) {
        float lg = colmode ? logits[(size_t)x * LL + rc] : logits[(size_t)rc * LL + x];
        wbuf[x] = expf(lg - M) * inv;
    }
    __syncthreads();
    int sub = t >> 4, q = t & 15;
    float4 acc = make_float4(0.f, 0.f, 0.f, 0.f);
    for (int base = 0; base < LL; base += 16) {
        int idx = base + sub;
        size_t pos = colmode ? ((size_t)idx * LL + rc) : ((size_t)rc * LL + idx);
        const float4 f = *reinterpret_cast<const float4*>(feat + pos * CT + q * 4);
        float w = wbuf[idx];
        acc.x += w * f.x; acc.y += w * f.y; acc.z += w * f.z; acc.w += w * f.w;
    }
    part[sub][q * 4 + 0] = acc.x;
    part[sub][q * 4 + 1] = acc.y;
    part[sub][q * 4 + 2] = acc.z;
    part[sub][q * 4 + 3] = acc.w;
    __syncthreads();
    if (t < 64) {
        float s = 0.f;
        #pragma unroll
        for (int k = 0; k < 16; ++k) s += part[k][t];
        rcfeat[(colmode ? LL * CT : 0) + rc * CT + t] = s;
    }
}

// ---------------- K4: diag gather + LN + (x @ W + b) [*sigma] ----------------
// blockIdx.y: 0 = left (WU,bU,sigma), 1 = right (WV,bV)
// left = LN(concat(d,r,c)); right = LN(concat(d,c,r)); mu/var identical.
__global__ __launch_bounds__(256) void k_final(const float* __restrict__ feat,
                                               const float* __restrict__ rcfeat,
                                               const float* __restrict__ ln_g,
                                               const float* __restrict__ ln_b,
                                               const float* __restrict__ WU,
                                               const float* __restrict__ bU,
                                               const float* __restrict__ WV,
                                               const float* __restrict__ bV,
                                               const float* __restrict__ sigma,
                                               float* __restrict__ out) {
    __shared__ float xbuf[8][KD];
    int t = threadIdx.x;
    int wid = t >> 6, l = t & 63;
    int r0 = blockIdx.x * 8;
    int right = blockIdx.y;
    const float* rfeat = rcfeat;
    const float* cfeat = rcfeat + LL * CT;

    for (int r = wid; r < 8; r += 4) {
        int i = r0 + r;
        float d  = feat[((size_t)i * LL + i) * CT + l];
        float rv = rfeat[i * CT + l];
        float cv = cfeat[i * CT + l];
        float sum = d + rv + cv;
        #pragma unroll
        for (int o = 32; o; o >>= 1) sum += __shfl_xor(sum, o);
        float mu = sum * (1.0f / 192.0f);
        float d0 = d - mu, d1 = rv - mu, d2 = cv - mu;
        float sq = d0 * d0 + d1 * d1 + d2 * d2;
        #pragma unroll
        for (int o = 32; o; o >>= 1) sq += __shfl_xor(sq, o);
        float rstd = rsqrtf(sq * (1.0f / 192.0f) + 1e-5f);
        float h0 = d0 * rstd, h1 = d1 * rstd, h2 = d2 * rstd;
        float a1 = right ? h2 : h1;   // position 64..127: left=row, right=col
        float a2 = right ? h1 : h2;   // position 128..191: left=col, right=row
        xbuf[r][l]       = h0 * ln_g[l]       + ln_b[l];
        xbuf[r][64 + l]  = a1 * ln_g[64 + l]  + ln_b[64 + l];
        xbuf[r][128 + l] = a2 * ln_g[128 + l] + ln_b[128 + l];
    }
    __syncthreads();

    const float* W    = right ? WV : WU;
    const float* bias = right ? bV : bU;
    int o = t * 4;
    float4 acc[8];
    #pragma unroll
    for (int r = 0; r < 8; ++r) acc[r] = make_float4(0.f, 0.f, 0.f, 0.f);

    for (int k = 0; k < KD; k += 4) {
        float4 xr[8];
        #pragma unroll
        for (int r = 0; r < 8; ++r)
            xr[r] = *reinterpret_cast<const float4*>(&xbuf[r][k]);
        #pragma unroll
        for (int kk = 0; kk < 4; ++kk) {
            float4 w = *reinterpret_cast<const float4*>(W + (size_t)(k + kk) * OC + o);
            #pragma unroll
            for (int r = 0; r < 8; ++r) {
                float xv = (&xr[r].x)[kk];
                acc[r].x = fmaf(xv, w.x, acc[r].x);
                acc[r].y = fmaf(xv, w.y, acc[r].y);
                acc[r].z = fmaf(xv, w.z, acc[r].z);
                acc[r].w = fmaf(xv, w.w, acc[r].w);
            }
        }
    }

    float4 bb = *reinterpret_cast<const float4*>(bias + o);
    float sg = right ? 1.0f : sigma[o >> 7];
    float* obase = out + (right ? (size_t)LL * OC : 0);
    #pragma unroll
    for (int r = 0; r < 8; ++r) {
        float4 v;
        v.x = (acc[r].x + bb.x) * sg;
        v.y = (acc[r].y + bb.y) * sg;
        v.z = (acc[r].z + bb.z) * sg;
        v.w = (acc[r].w + bb.w) * sg;
        *reinterpret_cast<float4*>(obase + (size_t)(r0 + r) * OC + o) = v;
    }
}

extern "C" void kernel_launch(void* const* d_in, const int* in_sizes, int n_in,
                              void* d_out, int out_size, void* d_ws, size_t ws_size,
                              hipStream_t stream) {
    const float* feat  = (const float*)d_in[0];
    const float* Wq    = (const float*)d_in[1];
    const float* bq    = (const float*)d_in[2];
    const float* ln_g  = (const float*)d_in[3];
    const float* ln_b  = (const float*)d_in[4];
    const float* WU    = (const float*)d_in[5];
    const float* bU    = (const float*)d_in[6];
    const float* WV    = (const float*)d_in[7];
    const float* bV    = (const float*)d_in[8];
    const float* sigma = (const float*)d_in[9];
    float* out = (float*)d_out;

    float* ws     = (float*)d_ws;
    float* logits = ws;                 // LL*LL
    float* stats  = ws + LL * LL;       // 4*LL
    float* rcfeat = stats + 4 * LL;     // 2*LL*CT

    hipLaunchKernelGGL(k_logits, dim3(LL * LL / 16), dim3(256), 0, stream,
                       feat, Wq, bq, logits);
    hipLaunchKernelGGL(k_stats, dim3(LL), dim3(256), 0, stream, logits, stats);
    hipLaunchKernelGGL(k_wsum, dim3(2 * LL), dim3(256), 0, stream,
                       feat, logits, stats, rcfeat);
    hipLaunchKernelGGL(k_final, dim3(LL / 8, 2), dim3(256), 0, stream,
                       feat, rcfeat, ln_g, ln_b, WU, bU, WV, bV, sigma, out);
}

// Round 2
// 110.838 us; speedup vs baseline: 1.0849x; 1.0849x over previous
//
#include <hip/hip_runtime.h>
#include <math.h>

#define LL 768
#define CT 64
#define KD 192
#define OC 1024
#define NCOLB (LL / 4)   // 192 col-strip blocks

// ---------------- K1: logits[i*LL+j] = dot(feat[i,j,:], Wq) + bq ----------------
__global__ __launch_bounds__(256) void k_logits(const float* __restrict__ feat,
                                                const float* __restrict__ Wq,
                                                const float* __restrict__ bq,
                                                float* __restrict__ logits) {
    int t = threadIdx.x;
    int p = blockIdx.x * 16 + (t >> 4);   // flat (i*LL + j)
    int q = t & 15;
    const float4 f = *reinterpret_cast<const float4*>(feat + (size_t)p * CT + q * 4);
    const float4 w = *reinterpret_cast<const float4*>(Wq + q * 4);
    float s = f.x * w.x + f.y * w.y + f.z * w.z + f.w * w.w;
    s += __shfl_xor(s, 1);
    s += __shfl_xor(s, 2);
    s += __shfl_xor(s, 4);
    s += __shfl_xor(s, 8);
    if (q == 0) logits[p] = s + bq[0];
}

// ---------------- K2: merged weighted sums, stats inline ----------------
// blocks [0, NCOLB): col strips of 4 columns each (started first: 4x work of a row block)
// blocks [NCOLB, NCOLB+LL): one row each
// rcfeat: [0, LL*CT) = row_feat, [LL*CT, 2*LL*CT) = col_feat
__global__ __launch_bounds__(256) void k_wsum2(const float* __restrict__ feat,
                                               const float* __restrict__ logits,
                                               float* __restrict__ rcfeat) {
    __shared__ float wcol[LL][5];        // exp weights, 4 cols (padded stride 5)
    __shared__ float part[16][64];       // cross-wave reduce
    __shared__ float redm[4], reds[4];
    __shared__ float sinv[4];

    int t = threadIdx.x;
    int b = blockIdx.x;

    if (b < NCOLB) {
        // ================= COLUMN STRIP: cols j0..j0+3 =================
        int j0 = b * 4;
        int jl = t >> 6;          // wave id = which column (prologue)
        int li = t & 63;

        // --- col stats + exp weights (strided logits reads, L2-hot) ---
        float m = -1e30f;
        #pragma unroll
        for (int k = 0; k < 12; ++k) {
            int i = li + k * 64;
            float v = logits[(size_t)i * LL + j0 + jl];
            wcol[i][jl] = v;
            m = fmaxf(m, v);
        }
        #pragma unroll
        for (int o = 32; o; o >>= 1) m = fmaxf(m, __shfl_xor(m, o));
        float s = 0.f;
        #pragma unroll
        for (int k = 0; k < 12; ++k) {
            int i = li + k * 64;
            float e = expf(wcol[i][jl] - m);
            wcol[i][jl] = e;
            s += e;
        }
        #pragma unroll
        for (int o = 32; o; o >>= 1) s += __shfl_xor(s, o);
        if (li == 0) sinv[jl] = 1.0f / s;
        __syncthreads();

        // --- main: wave w handles i = ib + w; 1KB contiguous per wave load ---
        int i_sub = t >> 6;
        int jlm = (t >> 4) & 3;
        int q = t & 15;
        const float* ptr = feat + ((size_t)i_sub * LL + j0 + jlm) * CT + q * 4;
        float4 acc = make_float4(0.f, 0.f, 0.f, 0.f);
        for (int ib = 0; ib < LL; ib += 4) {
            float ww = wcol[ib + i_sub][jlm];
            const float4 f = *reinterpret_cast<const float4*>(ptr);
            acc.x = fmaf(ww, f.x, acc.x);
            acc.y = fmaf(ww, f.y, acc.y);
            acc.z = fmaf(ww, f.z, acc.z);
            acc.w = fmaf(ww, f.w, acc.w);
            ptr += (size_t)4 * LL * CT;
        }
        // reduce over the 4 waves (i_sub)
        float* pp = &part[0][0] + ((i_sub * 4 + jlm) * 64 + q * 4);
        pp[0] = acc.x; pp[1] = acc.y; pp[2] = acc.z; pp[3] = acc.w;
        __syncthreads();
        int jl2 = t >> 6, c = t & 63;
        const float* p0 = &part[0][0];
        float r = p0[(jl2) * 64 + c] + p0[(4 + jl2) * 64 + c]
                + p0[(8 + jl2) * 64 + c] + p0[(12 + jl2) * 64 + c];
        rcfeat[(size_t)LL * CT + (j0 + jl2) * CT + c] = r * sinv[jl2];
    } else {
        // ================= ROW: row rc =================
        int rc = b - NCOLB;
        int wid = t >> 6;
        float* wr = &wcol[0][0];     // reuse as wr[768]

        // --- row stats + exp weights (sequential logits row) ---
        const float* lrow = logits + (size_t)rc * LL;
        float v0 = lrow[t], v1 = lrow[t + 256], v2 = lrow[t + 512];
        float m = fmaxf(fmaxf(v0, v1), v2);
        #pragma unroll
        for (int o = 32; o; o >>= 1) m = fmaxf(m, __shfl_xor(m, o));
        if ((t & 63) == 0) redm[wid] = m;
        __syncthreads();
        float M = fmaxf(fmaxf(redm[0], redm[1]), fmaxf(redm[2], redm[3]));
        float e0 = expf(v0 - M), e1 = expf(v1 - M), e2 = expf(v2 - M);
        wr[t] = e0; wr[t + 256] = e1; wr[t + 512] = e2;
        float s = e0 + e1 + e2;
        #pragma unroll
        for (int o = 32; o; o >>= 1) s += __shfl_xor(s, o);
        if ((t & 63) == 0) reds[wid] = s;
        __syncthreads();
        float inv = 1.0f / (reds[0] + reds[1] + reds[2] + reds[3]);

        // --- main: 4KB contiguous per block iteration ---
        int sub = t >> 4, q = t & 15;
        const float* ptr = feat + ((size_t)rc * LL + sub) * CT + q * 4;
        float4 acc = make_float4(0.f, 0.f, 0.f, 0.f);
        for (int jb = 0; jb < LL; jb += 16) {
            float ww = wr[jb + sub];
            const float4 f = *reinterpret_cast<const float4*>(ptr);
            acc.x = fmaf(ww, f.x, acc.x);
            acc.y = fmaf(ww, f.y, acc.y);
            acc.z = fmaf(ww, f.z, acc.z);
            acc.w = fmaf(ww, f.w, acc.w);
            ptr += 16 * CT;
        }
        float* pp = &part[0][0] + (sub * 64 + q * 4);
        pp[0] = acc.x; pp[1] = acc.y; pp[2] = acc.z; pp[3] = acc.w;
        __syncthreads();
        if (t < 64) {
            float r = 0.f;
            #pragma unroll
            for (int k = 0; k < 16; ++k) r += part[k][t];
            rcfeat[(size_t)rc * CT + t] = r * inv;
        }
    }
}

// ---------------- K4: diag gather + LN + (x @ W + b) [*sigma] ----------------
__global__ __launch_bounds__(256) void k_final(const float* __restrict__ feat,
                                               const float* __restrict__ rcfeat,
                                               const float* __restrict__ ln_g,
                                               const float* __restrict__ ln_b,
                                               const float* __restrict__ WU,
                                               const float* __restrict__ bU,
                                               const float* __restrict__ WV,
                                               const float* __restrict__ bV,
                                               const float* __restrict__ sigma,
                                               float* __restrict__ out) {
    __shared__ float xbuf[8][KD];
    int t = threadIdx.x;
    int wid = t >> 6, l = t & 63;
    int r0 = blockIdx.x * 8;
    int right = blockIdx.y;
    const float* rfeat = rcfeat;
    const float* cfeat = rcfeat + LL * CT;

    for (int r = wid; r < 8; r += 4) {
        int i = r0 + r;
        float d  = feat[((size_t)i * LL + i) * CT + l];
        float rv = rfeat[i * CT + l];
        float cv = cfeat[i * CT + l];
        float sum = d + rv + cv;
        #pragma unroll
        for (int o = 32; o; o >>= 1) sum += __shfl_xor(sum, o);
        float mu = sum * (1.0f / 192.0f);
        float d0 = d - mu, d1 = rv - mu, d2 = cv - mu;
        float sq = d0 * d0 + d1 * d1 + d2 * d2;
        #pragma unroll
        for (int o = 32; o; o >>= 1) sq += __shfl_xor(sq, o);
        float rstd = rsqrtf(sq * (1.0f / 192.0f) + 1e-5f);
        float h0 = d0 * rstd, h1 = d1 * rstd, h2 = d2 * rstd;
        float a1 = right ? h2 : h1;
        float a2 = right ? h1 : h2;
        xbuf[r][l]       = h0 * ln_g[l]       + ln_b[l];
        xbuf[r][64 + l]  = a1 * ln_g[64 + l]  + ln_b[64 + l];
        xbuf[r][128 + l] = a2 * ln_g[128 + l] + ln_b[128 + l];
    }
    __syncthreads();

    const float* W    = right ? WV : WU;
    const float* bias = right ? bV : bU;
    int o = t * 4;
    float4 acc[8];
    #pragma unroll
    for (int r = 0; r < 8; ++r) acc[r] = make_float4(0.f, 0.f, 0.f, 0.f);

    for (int k = 0; k < KD; k += 4) {
        float4 xr[8];
        #pragma unroll
        for (int r = 0; r < 8; ++r)
            xr[r] = *reinterpret_cast<const float4*>(&xbuf[r][k]);
        #pragma unroll
        for (int kk = 0; kk < 4; ++kk) {
            float4 w = *reinterpret_cast<const float4*>(W + (size_t)(k + kk) * OC + o);
            #pragma unroll
            for (int r = 0; r < 8; ++r) {
                float xv = (&xr[r].x)[kk];
                acc[r].x = fmaf(xv, w.x, acc[r].x);
                acc[r].y = fmaf(xv, w.y, acc[r].y);
                acc[r].z = fmaf(xv, w.z, acc[r].z);
                acc[r].w = fmaf(xv, w.w, acc[r].w);
            }
        }
    }

    float4 bb = *reinterpret_cast<const float4*>(bias + o);
    float sg = right ? 1.0f : sigma[o >> 7];
    float* obase = out + (right ? (size_t)LL * OC : 0);
    #pragma unroll
    for (int r = 0; r < 8; ++r) {
        float4 v;
        v.x = (acc[r].x + bb.x) * sg;
        v.y = (acc[r].y + bb.y) * sg;
        v.z = (acc[r].z + bb.z) * sg;
        v.w = (acc[r].w + bb.w) * sg;
        *reinterpret_cast<float4*>(obase + (size_t)(r0 + r) * OC + o) = v;
    }
}

extern "C" void kernel_launch(void* const* d_in, const int* in_sizes, int n_in,
                              void* d_out, int out_size, void* d_ws, size_t ws_size,
                              hipStream_t stream) {
    const float* feat  = (const float*)d_in[0];
    const float* Wq    = (const float*)d_in[1];
    const float* bq    = (const float*)d_in[2];
    const float* ln_g  = (const float*)d_in[3];
    const float* ln_b  = (const float*)d_in[4];
    const float* WU    = (const float*)d_in[5];
    const float* bU    = (const float*)d_in[6];
    const float* WV    = (const float*)d_in[7];
    const float* bV    = (const float*)d_in[8];
    const float* sigma = (const float*)d_in[9];
    float* out = (float*)d_out;

    float* ws     = (float*)d_ws;
    float* logits = ws;                 // LL*LL
    float* rcfeat = ws + LL * LL;       // 2*LL*CT

    hipLaunchKernelGGL(k_logits, dim3(LL * LL / 16), dim3(256), 0, stream,
                       feat, Wq, bq, logits);
    hipLaunchKernelGGL(k_wsum2, dim3(NCOLB + LL), dim3(256), 0, stream,
                       feat, logits, rcfeat);
    hipLaunchKernelGGL(k_final, dim3(LL / 8, 2), dim3(256), 0, stream,
                       feat, rcfeat, ln_g, ln_b, WU, bU, WV, bV, sigma, out);
}

// Round 3
// 103.992 us; speedup vs baseline: 1.1564x; 1.0658x over previous
//
#include <hip/hip_runtime.h>
#include <math.h>

#define LL 768
#define CT 64
#define KD 192
#define OC 1024
#define NST 48          // 48 strips of 16 in each dim

// ---------------- K1: logits[i*LL+j] = dot(feat[i,j,:], Wq) + bq ----------------
__global__ __launch_bounds__(256) void k_logits(const float* __restrict__ feat,
                                                const float* __restrict__ Wq,
                                                const float* __restrict__ bq,
                                                float* __restrict__ logits) {
    int t = threadIdx.x;
    int p = blockIdx.x * 16 + (t >> 4);
    int q = t & 15;
    const float4 f = *reinterpret_cast<const float4*>(feat + (size_t)p * CT + q * 4);
    const float4 w = *reinterpret_cast<const float4*>(Wq + q * 4);
    float s = f.x * w.x + f.y * w.y + f.z * w.z + f.w * w.w;
    s += __shfl_xor(s, 1);
    s += __shfl_xor(s, 2);
    s += __shfl_xor(s, 4);
    s += __shfl_xor(s, 8);
    if (q == 0) logits[p] = s + bq[0];
}

// ---------------- K2: stats[b]=rmax, [LL+b]=1/rsum, [2LL+b]=cmax, [3LL+b]=1/csum --
__global__ __launch_bounds__(256) void k_stats(const float* __restrict__ logits,
                                               float* __restrict__ stats) {
    __shared__ float redm[4], reds[4];
    int b = blockIdx.x, t = threadIdx.x;
    int wid = t >> 6;

    float v0 = logits[b * LL + t];
    float v1 = logits[b * LL + t + 256];
    float v2 = logits[b * LL + t + 512];
    float m = fmaxf(fmaxf(v0, v1), v2);
    #pragma unroll
    for (int o = 32; o; o >>= 1) m = fmaxf(m, __shfl_xor(m, o));
    if ((t & 63) == 0) redm[wid] = m;
    __syncthreads();
    float M = fmaxf(fmaxf(redm[0], redm[1]), fmaxf(redm[2], redm[3]));
    float s = expf(v0 - M) + expf(v1 - M) + expf(v2 - M);
    #pragma unroll
    for (int o = 32; o; o >>= 1) s += __shfl_xor(s, o);
    if ((t & 63) == 0) reds[wid] = s;
    __syncthreads();
    if (t == 0) {
        stats[b] = M;
        stats[LL + b] = 1.0f / (reds[0] + reds[1] + reds[2] + reds[3]);
    }
    __syncthreads();

    v0 = logits[(size_t)t * LL + b];
    v1 = logits[(size_t)(t + 256) * LL + b];
    v2 = logits[(size_t)(t + 512) * LL + b];
    m = fmaxf(fmaxf(v0, v1), v2);
    #pragma unroll
    for (int o = 32; o; o >>= 1) m = fmaxf(m, __shfl_xor(m, o));
    if ((t & 63) == 0) redm[wid] = m;
    __syncthreads();
    M = fmaxf(fmaxf(redm[0], redm[1]), fmaxf(redm[2], redm[3]));
    s = expf(v0 - M) + expf(v1 - M) + expf(v2 - M);
    #pragma unroll
    for (int o = 32; o; o >>= 1) s += __shfl_xor(s, o);
    if ((t & 63) == 0) reds[wid] = s;
    __syncthreads();
    if (t == 0) {
        stats[2 * LL + b] = M;
        stats[3 * LL + b] = 1.0f / (reds[0] + reds[1] + reds[2] + reds[3]);
    }
}

// ---------------- K3: single feat pass -> row partials + col partials ----------
// block (bi,bj) covers rows i0..i0+15, cols j0..j0+15, all 64 channels.
// thread (u = t>>4, q = t&15): row i0+u, channel-quad q; iterates j=(u+k)&15
// (stagger -> same-wave lanes hit distinct cpart[j] -> race-free LDS RMW).
// rp[bj][i*CT+c], cp[bi][j*CT+c] partials in workspace.
__global__ __launch_bounds__(256) void k_wsum3(const float* __restrict__ feat,
                                               const float* __restrict__ logits,
                                               const float* __restrict__ stats,
                                               float* __restrict__ rp,
                                               float* __restrict__ cp) {
    __shared__ float er[16][17];
    __shared__ float ec[16][17];
    __shared__ float cpart[4][16][72];   // [wave][j][c pad 72]

    int t = threadIdx.x;
    int u = t >> 4, q = t & 15;
    int w = t >> 6;
    int i0 = blockIdx.x * 16, j0 = blockIdx.y * 16;

    // weights (er/ec rows used only by the wave that wrote them)
    {
        int i = i0 + u, j = j0 + q;
        float lg = logits[(size_t)i * LL + j];
        er[u][q] = expf(lg - stats[i]) * stats[LL + i];
        ec[u][q] = expf(lg - stats[2 * LL + j]) * stats[3 * LL + j];
    }
    // zero cpart (flat, all threads)
    float4* cz = reinterpret_cast<float4*>(&cpart[0][0][0]);
    #pragma unroll
    for (int x = 0; x < 5; ++x) {
        int idx = t + x * 256;
        if (idx < 4 * 16 * 72 / 4) cz[idx] = make_float4(0.f, 0.f, 0.f, 0.f);
    }
    __syncthreads();

    const float* fbase = feat + ((size_t)(i0 + u) * LL + j0) * CT + q * 4;
    float4 racc = make_float4(0.f, 0.f, 0.f, 0.f);
    #pragma unroll 4
    for (int k = 0; k < 16; ++k) {
        int j = (u + k) & 15;
        const float4 f = *reinterpret_cast<const float4*>(fbase + j * CT);
        float wr = er[u][j];
        float wc = ec[u][j];
        racc.x = fmaf(wr, f.x, racc.x);
        racc.y = fmaf(wr, f.y, racc.y);
        racc.z = fmaf(wr, f.z, racc.z);
        racc.w = fmaf(wr, f.w, racc.w);
        float4* cpp = reinterpret_cast<float4*>(&cpart[w][j][q * 4]);
        float4 cv = *cpp;
        cv.x = fmaf(wc, f.x, cv.x);
        cv.y = fmaf(wc, f.y, cv.y);
        cv.z = fmaf(wc, f.z, cv.z);
        cv.w = fmaf(wc, f.w, cv.w);
        *cpp = cv;
    }
    // row partials: complete over this block's 16 j
    *reinterpret_cast<float4*>(rp + (size_t)blockIdx.y * (LL * CT)
                               + (i0 + u) * CT + q * 4) = racc;
    __syncthreads();
    // col partials: reduce 4 waves
    {
        int j = t >> 4, c4 = t & 15;
        float4 a = *reinterpret_cast<const float4*>(&cpart[0][j][c4 * 4]);
        const float4 b1 = *reinterpret_cast<const float4*>(&cpart[1][j][c4 * 4]);
        const float4 b2 = *reinterpret_cast<const float4*>(&cpart[2][j][c4 * 4]);
        const float4 b3 = *reinterpret_cast<const float4*>(&cpart[3][j][c4 * 4]);
        a.x += b1.x + b2.x + b3.x;
        a.y += b1.y + b2.y + b3.y;
        a.z += b1.z + b2.z + b3.z;
        a.w += b1.w + b2.w + b3.w;
        *reinterpret_cast<float4*>(cp + (size_t)blockIdx.x * (LL * CT)
                                   + (j0 + j) * CT + c4 * 4) = a;
    }
}

// ---------------- K3b: fold 48 partials -> rcfeat ----------------
__global__ __launch_bounds__(256) void k_reduce(const float* __restrict__ rp,
                                                const float* __restrict__ cp,
                                                float* __restrict__ rcfeat) {
    int tid = blockIdx.x * 256 + threadIdx.x;   // [0, 24576)
    int half = tid >= (LL * CT / 4);
    int o = half ? tid - LL * CT / 4 : tid;
    const float* base = (half ? cp : rp) + (size_t)o * 4;
    float4 a0 = make_float4(0.f, 0.f, 0.f, 0.f);
    float4 a1 = make_float4(0.f, 0.f, 0.f, 0.f);
    float4 a2 = make_float4(0.f, 0.f, 0.f, 0.f);
    float4 a3 = make_float4(0.f, 0.f, 0.f, 0.f);
    #pragma unroll
    for (int s = 0; s < NST; s += 4) {
        const float4 v0 = *reinterpret_cast<const float4*>(base + (size_t)(s + 0) * LL * CT);
        const float4 v1 = *reinterpret_cast<const float4*>(base + (size_t)(s + 1) * LL * CT);
        const float4 v2 = *reinterpret_cast<const float4*>(base + (size_t)(s + 2) * LL * CT);
        const float4 v3 = *reinterpret_cast<const float4*>(base + (size_t)(s + 3) * LL * CT);
        a0.x += v0.x; a0.y += v0.y; a0.z += v0.z; a0.w += v0.w;
        a1.x += v1.x; a1.y += v1.y; a1.z += v1.z; a1.w += v1.w;
        a2.x += v2.x; a2.y += v2.y; a2.z += v2.z; a2.w += v2.w;
        a3.x += v3.x; a3.y += v3.y; a3.z += v3.z; a3.w += v3.w;
    }
    float4 r;
    r.x = (a0.x + a1.x) + (a2.x + a3.x);
    r.y = (a0.y + a1.y) + (a2.y + a3.y);
    r.z = (a0.z + a1.z) + (a2.z + a3.z);
    r.w = (a0.w + a1.w) + (a2.w + a3.w);
    *reinterpret_cast<float4*>(rcfeat + (size_t)tid * 4) = r;
}

// ---------------- K4: diag gather + LN + (x @ W + b) [*sigma] ----------------
__global__ __launch_bounds__(256) void k_final(const float* __restrict__ feat,
                                               const float* __restrict__ rcfeat,
                                               const float* __restrict__ ln_g,
                                               const float* __restrict__ ln_b,
                                               const float* __restrict__ WU,
                                               const float* __restrict__ bU,
                                               const float* __restrict__ WV,
                                               const float* __restrict__ bV,
                                               const float* __restrict__ sigma,
                                               float* __restrict__ out) {
    __shared__ float xbuf[8][KD];
    int t = threadIdx.x;
    int wid = t >> 6, l = t & 63;
    int r0 = blockIdx.x * 8;
    int right = blockIdx.y;
    const float* rfeat = rcfeat;
    const float* cfeat = rcfeat + LL * CT;

    for (int r = wid; r < 8; r += 4) {
        int i = r0 + r;
        float d  = feat[((size_t)i * LL + i) * CT + l];
        float rv = rfeat[i * CT + l];
        float cv = cfeat[i * CT + l];
        float sum = d + rv + cv;
        #pragma unroll
        for (int o = 32; o; o >>= 1) sum += __shfl_xor(sum, o);
        float mu = sum * (1.0f / 192.0f);
        float d0 = d - mu, d1 = rv - mu, d2 = cv - mu;
        float sq = d0 * d0 + d1 * d1 + d2 * d2;
        #pragma unroll
        for (int o = 32; o; o >>= 1) sq += __shfl_xor(sq, o);
        float rstd = rsqrtf(sq * (1.0f / 192.0f) + 1e-5f);
        float h0 = d0 * rstd, h1 = d1 * rstd, h2 = d2 * rstd;
        float a1 = right ? h2 : h1;
        float a2 = right ? h1 : h2;
        xbuf[r][l]       = h0 * ln_g[l]       + ln_b[l];
        xbuf[r][64 + l]  = a1 * ln_g[64 + l]  + ln_b[64 + l];
        xbuf[r][128 + l] = a2 * ln_g[128 + l] + ln_b[128 + l];
    }
    __syncthreads();

    const float* W    = right ? WV : WU;
    const float* bias = right ? bV : bU;
    int o = t * 4;
    float4 acc[8];
    #pragma unroll
    for (int r = 0; r < 8; ++r) acc[r] = make_float4(0.f, 0.f, 0.f, 0.f);

    for (int k = 0; k < KD; k += 4) {
        float4 xr[8];
        #pragma unroll
        for (int r = 0; r < 8; ++r)
            xr[r] = *reinterpret_cast<const float4*>(&xbuf[r][k]);
        #pragma unroll
        for (int kk = 0; kk < 4; ++kk) {
            float4 w = *reinterpret_cast<const float4*>(W + (size_t)(k + kk) * OC + o);
            #pragma unroll
            for (int r = 0; r < 8; ++r) {
                float xv = (&xr[r].x)[kk];
                acc[r].x = fmaf(xv, w.x, acc[r].x);
                acc[r].y = fmaf(xv, w.y, acc[r].y);
                acc[r].z = fmaf(xv, w.z, acc[r].z);
                acc[r].w = fmaf(xv, w.w, acc[r].w);
            }
        }
    }

    float4 bb = *reinterpret_cast<const float4*>(bias + o);
    float sg = right ? 1.0f : sigma[o >> 7];
    float* obase = out + (right ? (size_t)LL * OC : 0);
    #pragma unroll
    for (int r = 0; r < 8; ++r) {
        float4 v;
        v.x = (acc[r].x + bb.x) * sg;
        v.y = (acc[r].y + bb.y) * sg;
        v.z = (acc[r].z + bb.z) * sg;
        v.w = (acc[r].w + bb.w) * sg;
        *reinterpret_cast<float4*>(obase + (size_t)(r0 + r) * OC + o) = v;
    }
}

extern "C" void kernel_launch(void* const* d_in, const int* in_sizes, int n_in,
                              void* d_out, int out_size, void* d_ws, size_t ws_size,
                              hipStream_t stream) {
    const float* feat  = (const float*)d_in[0];
    const float* Wq    = (const float*)d_in[1];
    const float* bq    = (const float*)d_in[2];
    const float* ln_g  = (const float*)d_in[3];
    const float* ln_b  = (const float*)d_in[4];
    const float* WU    = (const float*)d_in[5];
    const float* bU    = (const float*)d_in[6];
    const float* WV    = (const float*)d_in[7];
    const float* bV    = (const float*)d_in[8];
    const float* sigma = (const float*)d_in[9];
    float* out = (float*)d_out;

    float* ws     = (float*)d_ws;
    float* logits = ws;                                  // LL*LL
    float* stats  = logits + (size_t)LL * LL;            // 4*LL
    float* rp     = stats + 4 * LL;                      // NST*LL*CT
    float* cp     = rp + (size_t)NST * LL * CT;          // NST*LL*CT
    float* rcfeat = cp + (size_t)NST * LL * CT;          // 2*LL*CT

    hipLaunchKernelGGL(k_logits, dim3(LL * LL / 16), dim3(256), 0, stream,
                       feat, Wq, bq, logits);
    hipLaunchKernelGGL(k_stats, dim3(LL), dim3(256), 0, stream, logits, stats);
    hipLaunchKernelGGL(k_wsum3, dim3(NST, NST), dim3(256), 0, stream,
                       feat, logits, stats, rp, cp);
    hipLaunchKernelGGL(k_reduce, dim3(2 * LL * CT / 4 / 256), dim3(256), 0, stream,
                       rp, cp, rcfeat);
    hipLaunchKernelGGL(k_final, dim3(LL / 8, 2), dim3(256), 0, stream,
                       feat, rcfeat, ln_g, ln_b, WU, bU, WV, bV, sigma, out);
}

// Round 4
// 82.574 us; speedup vs baseline: 1.4563x; 1.2594x over previous
//
#include <hip/hip_runtime.h>
#include <math.h>

#define LL 768
#define CT 64
#define KD 192
#define OC 1024
#define TS 16
#define NST 48           // 768/16 tiles per dim
#define PCH 68           // partial row: 64 ch + z at [64], padded to 68

// ---------------- K1: fused logits+exp+row/col unnormalized sums, 1 feat pass ----
// tile (bi,bj): rows i0..i0+15, cols j0..j0+15.
// thread (u = t>>4 -> col j0+u, q = t&15 -> channel quad). wave w = t>>6 owns
// cols j0+4w..j0+4w+3; loops i over 16 rows; per iter loads 1KB contiguous.
// e_ij = exp(logit + bq) computed in-tile (no max subtraction: logits ~ N(0,1)).
// col partials: registers. row partials: shfl-reduce over the wave's 4 cols,
// single LDS write per (wave,row) (no RMW), cross-wave fold at tile end.
// rp[bj][row][PCH], cp[bi][col][PCH] with z at channel 64.
__global__ __launch_bounds__(256) void k_fused(const float* __restrict__ feat,
                                               const float* __restrict__ Wq,
                                               const float* __restrict__ bq,
                                               float* __restrict__ rp,
                                               float* __restrict__ cp) {
    __shared__ float rpart[4][TS][PCH];

    int t = threadIdx.x;
    int u = t >> 4, q = t & 15;
    int w = t >> 6;
    int i0 = blockIdx.x * TS, j0 = blockIdx.y * TS;

    const float4 wq = *reinterpret_cast<const float4*>(Wq + q * 4);
    const float bqv = bq[0];

    const float* fb = feat + ((size_t)i0 * LL + j0 + u) * CT + q * 4;
    float4 creg = make_float4(0.f, 0.f, 0.f, 0.f);
    float zc = 0.f;

    #pragma unroll 4
    for (int i = 0; i < TS; ++i) {
        const float4 f = *reinterpret_cast<const float4*>(fb);
        fb += (size_t)LL * CT;

        // rank-1 logit: reduce over the 16 q-lanes
        float s = f.x * wq.x + f.y * wq.y + f.z * wq.z + f.w * wq.w;
        s += __shfl_xor(s, 1);
        s += __shfl_xor(s, 2);
        s += __shfl_xor(s, 4);
        s += __shfl_xor(s, 8);
        float e = __expf(s + bqv);

        // p = e * f  (shared by row and col accumulation)
        float px = e * f.x, py = e * f.y, pz = e * f.z, pw = e * f.w;

        // col accumulation (this thread owns col j0+u, channels q*4..)
        creg.x += px; creg.y += py; creg.z += pz; creg.w += pw;
        zc += e;

        // row accumulation: sum over the wave's 4 cols (lanes xor 16, 32)
        px += __shfl_xor(px, 16); px += __shfl_xor(px, 32);
        py += __shfl_xor(py, 16); py += __shfl_xor(py, 32);
        pz += __shfl_xor(pz, 16); pz += __shfl_xor(pz, 32);
        pw += __shfl_xor(pw, 16); pw += __shfl_xor(pw, 32);
        float ze = e;
        ze += __shfl_xor(ze, 16); ze += __shfl_xor(ze, 32);

        if ((t & 48) == 0) {               // first u of each wave, 16 q-lanes
            float4* dst = reinterpret_cast<float4*>(&rpart[w][i][q * 4]);
            *dst = make_float4(px, py, pz, pw);
            if (q == 0) rpart[w][i][64] = ze;
        }
    }
    __syncthreads();

    // col partials out (registers -> global, written once)
    {
        size_t cpo = ((size_t)blockIdx.x * LL + (j0 + u)) * PCH;
        *reinterpret_cast<float4*>(cp + cpo + q * 4) = creg;
        if (q == 0) cp[cpo + 64] = zc;
    }
    // row partials: fold 4 waves, out
    {
        int r = u;
        float4 a  = *reinterpret_cast<const float4*>(&rpart[0][r][q * 4]);
        const float4 b1 = *reinterpret_cast<const float4*>(&rpart[1][r][q * 4]);
        const float4 b2 = *reinterpret_cast<const float4*>(&rpart[2][r][q * 4]);
        const float4 b3 = *reinterpret_cast<const float4*>(&rpart[3][r][q * 4]);
        a.x += b1.x + b2.x + b3.x;
        a.y += b1.y + b2.y + b3.y;
        a.z += b1.z + b2.z + b3.z;
        a.w += b1.w + b2.w + b3.w;
        size_t rpo = ((size_t)blockIdx.y * LL + (i0 + r)) * PCH;
        *reinterpret_cast<float4*>(rp + rpo + q * 4) = a;
        if (q == 0)
            rp[rpo + 64] = rpart[0][r][64] + rpart[1][r][64]
                         + rpart[2][r][64] + rpart[3][r][64];
    }
}

// ---------------- K2: fold 48 strip-partials, divide by z -> rcfeat ----------
// blockIdx.y: 0 = row side (rp), 1 = col side (cp). block handles 16 lines.
__global__ __launch_bounds__(256) void k_combine(const float* __restrict__ rp,
                                                 const float* __restrict__ cp,
                                                 float* __restrict__ rcfeat) {
    int t = threadIdx.x;
    int r = t >> 4, q = t & 15;
    int L0 = blockIdx.x * 16;
    int side = blockIdx.y;
    const float* base = side ? cp : rp;

    float4 acc = make_float4(0.f, 0.f, 0.f, 0.f);
    float z = 0.f;
    #pragma unroll 4
    for (int s = 0; s < NST; ++s) {
        const float* p = base + ((size_t)s * LL + L0 + r) * PCH;
        const float4 v = *reinterpret_cast<const float4*>(p + q * 4);
        acc.x += v.x; acc.y += v.y; acc.z += v.z; acc.w += v.w;
        z += p[64];
    }
    float inv = 1.0f / z;
    acc.x *= inv; acc.y *= inv; acc.z *= inv; acc.w *= inv;
    *reinterpret_cast<float4*>(rcfeat + (size_t)side * LL * CT
                               + (L0 + r) * CT + q * 4) = acc;
}

// ---------------- K3: diag gather + LN + (x @ W + b) [*sigma] ----------------
__global__ __launch_bounds__(256) void k_final(const float* __restrict__ feat,
                                               const float* __restrict__ rcfeat,
                                               const float* __restrict__ ln_g,
                                               const float* __restrict__ ln_b,
                                               const float* __restrict__ WU,
                                               const float* __restrict__ bU,
                                               const float* __restrict__ WV,
                                               const float* __restrict__ bV,
                                               const float* __restrict__ sigma,
                                               float* __restrict__ out) {
    __shared__ float xbuf[8][KD];
    int t = threadIdx.x;
    int wid = t >> 6, l = t & 63;
    int r0 = blockIdx.x * 8;
    int right = blockIdx.y;
    const float* rfeat = rcfeat;
    const float* cfeat = rcfeat + LL * CT;

    for (int r = wid; r < 8; r += 4) {
        int i = r0 + r;
        float d  = feat[((size_t)i * LL + i) * CT + l];
        float rv = rfeat[i * CT + l];
        float cv = cfeat[i * CT + l];
        float sum = d + rv + cv;
        #pragma unroll
        for (int o = 32; o; o >>= 1) sum += __shfl_xor(sum, o);
        float mu = sum * (1.0f / 192.0f);
        float d0 = d - mu, d1 = rv - mu, d2 = cv - mu;
        float sq = d0 * d0 + d1 * d1 + d2 * d2;
        #pragma unroll
        for (int o = 32; o; o >>= 1) sq += __shfl_xor(sq, o);
        float rstd = rsqrtf(sq * (1.0f / 192.0f) + 1e-5f);
        float h0 = d0 * rstd, h1 = d1 * rstd, h2 = d2 * rstd;
        float a1 = right ? h2 : h1;
        float a2 = right ? h1 : h2;
        xbuf[r][l]       = h0 * ln_g[l]       + ln_b[l];
        xbuf[r][64 + l]  = a1 * ln_g[64 + l]  + ln_b[64 + l];
        xbuf[r][128 + l] = a2 * ln_g[128 + l] + ln_b[128 + l];
    }
    __syncthreads();

    const float* W    = right ? WV : WU;
    const float* bias = right ? bV : bU;
    int o = t * 4;
    float4 acc[8];
    #pragma unroll
    for (int r = 0; r < 8; ++r) acc[r] = make_float4(0.f, 0.f, 0.f, 0.f);

    for (int k = 0; k < KD; k += 4) {
        float4 xr[8];
        #pragma unroll
        for (int r = 0; r < 8; ++r)
            xr[r] = *reinterpret_cast<const float4*>(&xbuf[r][k]);
        #pragma unroll
        for (int kk = 0; kk < 4; ++kk) {
            float4 w = *reinterpret_cast<const float4*>(W + (size_t)(k + kk) * OC + o);
            #pragma unroll
            for (int r = 0; r < 8; ++r) {
                float xv = (&xr[r].x)[kk];
                acc[r].x = fmaf(xv, w.x, acc[r].x);
                acc[r].y = fmaf(xv, w.y, acc[r].y);
                acc[r].z = fmaf(xv, w.z, acc[r].z);
                acc[r].w = fmaf(xv, w.w, acc[r].w);
            }
        }
    }

    float4 bb = *reinterpret_cast<const float4*>(bias + o);
    float sg = right ? 1.0f : sigma[o >> 7];
    float* obase = out + (right ? (size_t)LL * OC : 0);
    #pragma unroll
    for (int r = 0; r < 8; ++r) {
        float4 v;
        v.x = (acc[r].x + bb.x) * sg;
        v.y = (acc[r].y + bb.y) * sg;
        v.z = (acc[r].z + bb.z) * sg;
        v.w = (acc[r].w + bb.w) * sg;
        *reinterpret_cast<float4*>(obase + (size_t)(r0 + r) * OC + o) = v;
    }
}

extern "C" void kernel_launch(void* const* d_in, const int* in_sizes, int n_in,
                              void* d_out, int out_size, void* d_ws, size_t ws_size,
                              hipStream_t stream) {
    const float* feat  = (const float*)d_in[0];
    const float* Wq    = (const float*)d_in[1];
    const float* bq    = (const float*)d_in[2];
    const float* ln_g  = (const float*)d_in[3];
    const float* ln_b  = (const float*)d_in[4];
    const float* WU    = (const float*)d_in[5];
    const float* bU    = (const float*)d_in[6];
    const float* WV    = (const float*)d_in[7];
    const float* bV    = (const float*)d_in[8];
    const float* sigma = (const float*)d_in[9];
    float* out = (float*)d_out;

    float* ws     = (float*)d_ws;
    float* rp     = ws;                                  // NST*LL*PCH
    float* cp     = rp + (size_t)NST * LL * PCH;         // NST*LL*PCH
    float* rcfeat = cp + (size_t)NST * LL * PCH;         // 2*LL*CT

    hipLaunchKernelGGL(k_fused, dim3(NST, NST), dim3(256), 0, stream,
                       feat, Wq, bq, rp, cp);
    hipLaunchKernelGGL(k_combine, dim3(NST, 2), dim3(256), 0, stream,
                       rp, cp, rcfeat);
    hipLaunchKernelGGL(k_final, dim3(LL / 8, 2), dim3(256), 0, stream,
                       feat, rcfeat, ln_g, ln_b, WU, bU, WV, bV, sigma, out);
}

// Round 5
// 82.028 us; speedup vs baseline: 1.4660x; 1.0067x over previous
//
#include <hip/hip_runtime.h>
#include <math.h>

#define LL 768
#define CT 64
#define KD 192
#define OC 1024
#define TS 16
#define NST 48           // 768/16 tiles per dim
#define PCH 68           // partial line: 64 ch + z at [64], padded to 68

// ---------------- K1: fused logits+exp+row/col unnormalized sums, 1 feat pass ----
// tile (bi,bj) = rows i0..i0+15 x cols j0..j0+15. thread: u=t>>4 (col), q=t&15
// (channel quad). Per i-iter: 1KB/wave contiguous load, dot via 4 swizzles,
// e = exp(logit+bq) (no max-sub: logits ~ N(0,1)), col partials in registers,
// row contribution = single LDS write (each (i,j) visited once -> assignment,
// not accumulate). Two chunked LDS transpose-reduce phases fold over u.
// XCD-bijective block swizzle: each XCD gets 6 contiguous i-strips (18.9MB).
__global__ __launch_bounds__(256) void k_fused(const float* __restrict__ feat,
                                               const float* __restrict__ Wq,
                                               const float* __restrict__ bq,
                                               float* __restrict__ rp,
                                               float* __restrict__ cp) {
    __shared__ float4 lbuf[16][8][17];   // [u][ii][c4 pad 17] -> bank-uniform
    __shared__ float  zb[16][9];         // per-(u, ii) row-z contribution

    int t = threadIdx.x;
    int u = t >> 4, q = t & 15;

    // bijective XCD swizzle: 2304 = 8 * 288
    int bid = blockIdx.x;
    int nb = (bid & 7) * 288 + (bid >> 3);
    int bi = nb / NST, bj = nb % NST;
    int i0 = bi * TS, j0 = bj * TS;

    const float4 wq = *reinterpret_cast<const float4*>(Wq + q * 4);
    const float bqv = bq[0];

    const float* fb = feat + ((size_t)i0 * LL + j0 + u) * CT + q * 4;
    const size_t istr = (size_t)LL * CT;
    float4 creg = make_float4(0.f, 0.f, 0.f, 0.f);
    float zc = 0.f;

    for (int half = 0; half < 2; ++half) {
        #pragma unroll
        for (int ii = 0; ii < 8; ++ii) {
            const float4 f = *reinterpret_cast<const float4*>(fb + (half * 8 + ii) * istr);

            // rank-1 logit: reduce over the 16 q-lanes (only serial DS chain)
            float s = f.x * wq.x + f.y * wq.y + f.z * wq.z + f.w * wq.w;
            s += __shfl_xor(s, 1);
            s += __shfl_xor(s, 2);
            s += __shfl_xor(s, 4);
            s += __shfl_xor(s, 8);
            float e = __expf(s + bqv);

            float4 p;
            p.x = e * f.x; p.y = e * f.y; p.z = e * f.z; p.w = e * f.w;

            // col accumulation (register)
            creg.x += p.x; creg.y += p.y; creg.z += p.z; creg.w += p.w;
            zc += e;

            // row contribution: one LDS write, no reduce, no RMW
            lbuf[u][ii][q] = p;
            if (q == 0) zb[u][ii] = e;
        }
        __syncthreads();

        // fold row partials over the 16 u-columns
        if (t < 128) {
            int ii = t >> 4, c4 = t & 15;
            float4 a = make_float4(0.f, 0.f, 0.f, 0.f);
            #pragma unroll
            for (int uu = 0; uu < 16; ++uu) {
                const float4 v = lbuf[uu][ii][c4];
                a.x += v.x; a.y += v.y; a.z += v.z; a.w += v.w;
            }
            *reinterpret_cast<float4*>(rp + ((size_t)bj * LL + i0 + half * 8 + ii) * PCH
                                       + c4 * 4) = a;
        }
        if (t < 8) {
            float zz = 0.f;
            #pragma unroll
            for (int uu = 0; uu < 16; ++uu) zz += zb[uu][t];
            rp[((size_t)bj * LL + i0 + half * 8 + t) * PCH + 64] = zz;
        }
        __syncthreads();
    }

    // col partials out (registers -> global, once)
    size_t cpo = ((size_t)bi * LL + (j0 + u)) * PCH;
    *reinterpret_cast<float4*>(cp + cpo + q * 4) = creg;
    if (q == 0) cp[cpo + 64] = zc;
}

// ---------------- K2: fold 48 strip-partials, divide by z -> rcfeat ----------
__global__ __launch_bounds__(256) void k_combine(const float* __restrict__ rp,
                                                 const float* __restrict__ cp,
                                                 float* __restrict__ rcfeat) {
    int t = threadIdx.x;
    int r = t >> 4, q = t & 15;
    int L0 = blockIdx.x * 16;
    int side = blockIdx.y;
    const float* base = side ? cp : rp;

    float4 acc = make_float4(0.f, 0.f, 0.f, 0.f);
    float z = 0.f;
    #pragma unroll 4
    for (int s = 0; s < NST; ++s) {
        const float* p = base + ((size_t)s * LL + L0 + r) * PCH;
        const float4 v = *reinterpret_cast<const float4*>(p + q * 4);
        acc.x += v.x; acc.y += v.y; acc.z += v.z; acc.w += v.w;
        z += p[64];
    }
    float inv = 1.0f / z;
    acc.x *= inv; acc.y *= inv; acc.z *= inv; acc.w *= inv;
    *reinterpret_cast<float4*>(rcfeat + (size_t)side * LL * CT
                               + (L0 + r) * CT + q * 4) = acc;
}

// ---------------- K3: diag gather + LN + (x @ W + b) [*sigma] ----------------
__global__ __launch_bounds__(256) void k_final(const float* __restrict__ feat,
                                               const float* __restrict__ rcfeat,
                                               const float* __restrict__ ln_g,
                                               const float* __restrict__ ln_b,
                                               const float* __restrict__ WU,
                                               const float* __restrict__ bU,
                                               const float* __restrict__ WV,
                                               const float* __restrict__ bV,
                                               const float* __restrict__ sigma,
                                               float* __restrict__ out) {
    __shared__ float xbuf[8][KD];
    int t = threadIdx.x;
    int wid = t >> 6, l = t & 63;
    int r0 = blockIdx.x * 8;
    int right = blockIdx.y;
    const float* rfeat = rcfeat;
    const float* cfeat = rcfeat + LL * CT;

    for (int r = wid; r < 8; r += 4) {
        int i = r0 + r;
        float d  = feat[((size_t)i * LL + i) * CT + l];
        float rv = rfeat[i * CT + l];
        float cv = cfeat[i * CT + l];
        float sum = d + rv + cv;
        #pragma unroll
        for (int o = 32; o; o >>= 1) sum += __shfl_xor(sum, o);
        float mu = sum * (1.0f / 192.0f);
        float d0 = d - mu, d1 = rv - mu, d2 = cv - mu;
        float sq = d0 * d0 + d1 * d1 + d2 * d2;
        #pragma unroll
        for (int o = 32; o; o >>= 1) sq += __shfl_xor(sq, o);
        float rstd = rsqrtf(sq * (1.0f / 192.0f) + 1e-5f);
        float h0 = d0 * rstd, h1 = d1 * rstd, h2 = d2 * rstd;
        float a1 = right ? h2 : h1;
        float a2 = right ? h1 : h2;
        xbuf[r][l]       = h0 * ln_g[l]       + ln_b[l];
        xbuf[r][64 + l]  = a1 * ln_g[64 + l]  + ln_b[64 + l];
        xbuf[r][128 + l] = a2 * ln_g[128 + l] + ln_b[128 + l];
    }
    __syncthreads();

    const float* W    = right ? WV : WU;
    const float* bias = right ? bV : bU;
    int o = t * 4;
    float4 acc[8];
    #pragma unroll
    for (int r = 0; r < 8; ++r) acc[r] = make_float4(0.f, 0.f, 0.f, 0.f);

    for (int k = 0; k < KD; k += 4) {
        float4 xr[8];
        #pragma unroll
        for (int r = 0; r < 8; ++r)
            xr[r] = *reinterpret_cast<const float4*>(&xbuf[r][k]);
        #pragma unroll
        for (int kk = 0; kk < 4; ++kk) {
            float4 w = *reinterpret_cast<const float4*>(W + (size_t)(k + kk) * OC + o);
            #pragma unroll
            for (int r = 0; r < 8; ++r) {
                float xv = (&xr[r].x)[kk];
                acc[r].x = fmaf(xv, w.x, acc[r].x);
                acc[r].y = fmaf(xv, w.y, acc[r].y);
                acc[r].z = fmaf(xv, w.z, acc[r].z);
                acc[r].w = fmaf(xv, w.w, acc[r].w);
            }
        }
    }

    float4 bb = *reinterpret_cast<const float4*>(bias + o);
    float sg = right ? 1.0f : sigma[o >> 7];
    float* obase = out + (right ? (size_t)LL * OC : 0);
    #pragma unroll
    for (int r = 0; r < 8; ++r) {
        float4 v;
        v.x = (acc[r].x + bb.x) * sg;
        v.y = (acc[r].y + bb.y) * sg;
        v.z = (acc[r].z + bb.z) * sg;
        v.w = (acc[r].w + bb.w) * sg;
        *reinterpret_cast<float4*>(obase + (size_t)(r0 + r) * OC + o) = v;
    }
}

extern "C" void kernel_launch(void* const* d_in, const int* in_sizes, int n_in,
                              void* d_out, int out_size, void* d_ws, size_t ws_size,
                              hipStream_t stream) {
    const float* feat  = (const float*)d_in[0];
    const float* Wq    = (const float*)d_in[1];
    const float* bq    = (const float*)d_in[2];
    const float* ln_g  = (const float*)d_in[3];
    const float* ln_b  = (const float*)d_in[4];
    const float* WU    = (const float*)d_in[5];
    const float* bU    = (const float*)d_in[6];
    const float* WV    = (const float*)d_in[7];
    const float* bV    = (const float*)d_in[8];
    const float* sigma = (const float*)d_in[9];
    float* out = (float*)d_out;

    float* ws     = (float*)d_ws;
    float* rp     = ws;                                  // NST*LL*PCH
    float* cp     = rp + (size_t)NST * LL * PCH;         // NST*LL*PCH
    float* rcfeat = cp + (size_t)NST * LL * PCH;         // 2*LL*CT

    hipLaunchKernelGGL(k_fused, dim3(NST * NST), dim3(256), 0, stream,
                       feat, Wq, bq, rp, cp);
    hipLaunchKernelGGL(k_combine, dim3(NST, 2), dim3(256), 0, stream,
                       rp, cp, rcfeat);
    hipLaunchKernelGGL(k_final, dim3(LL / 8, 2), dim3(256), 0, stream,
                       feat, rcfeat, ln_g, ln_b, WU, bU, WV, bV, sigma, out);
}